// Round 1
// baseline (243.276 us; speedup 1.0000x reference)
//
#include <hip/hip_runtime.h>
#include <hip/hip_bf16.h>
#include <stdint.h>

#define DI __device__ __forceinline__

typedef float f32x4 __attribute__((ext_vector_type(4)));
typedef __bf16 bf16x8 __attribute__((ext_vector_type(8)));

static constexpr int M = 1024;
static constexpr int N = 4096;
static constexpr int K = 4096;

// ---------------- fake-quant (f32, exact ref semantics) -> bf16 ----------------
DI unsigned short f2bf(float f) {
  union { __hip_bfloat16 h; unsigned short u; } cv;
  cv.h = __float2bfloat16(f);  // RNE
  return cv.u;
}

DI float fq1(float x, float s, float z) {
  float q = rintf(x / s + z);             // round half-to-even, like jnp.round
  q = fminf(fmaxf(q, 0.0f), 255.0f);
  return (q - z) * s;
}

__global__ __launch_bounds__(256) void fq_kernel(
    const float* __restrict__ v, const float* __restrict__ scales,
    const float* __restrict__ zeros, unsigned short* __restrict__ out,
    unsigned smask, int n4) {
  int t = blockIdx.x * blockDim.x + threadIdx.x;
  if (t >= n4) return;
  int si = (int)((unsigned)t & smask);
  float s = scales[si], z = zeros[si];
  const float4 x = reinterpret_cast<const float4*>(v)[t];
  ushort4 o;
  o.x = f2bf(fq1(x.x, s, z));
  o.y = f2bf(fq1(x.y, s, z));
  o.z = f2bf(fq1(x.z, s, z));
  o.w = f2bf(fq1(x.w, s, z));
  reinterpret_cast<ushort4*>(out)[t] = o;
}

// ---------------- bf16 GEMM: C[M,N] = A[M,K] * B[N,K]^T + bias ----------------
static constexpr int BM = 64, BN = 128, BK = 64;
static constexpr int KT = K / BK;

DI void gl2lds16(const void* g, void* l) {
  __builtin_amdgcn_global_load_lds(
      (const __attribute__((address_space(1))) void*)g,
      (__attribute__((address_space(3))) void*)l, 16, 0, 0);
}

__global__ __launch_bounds__(256, 2) void gemm_kernel(
    const unsigned short* __restrict__ Aq,   // [M][K] bf16 bits
    const unsigned short* __restrict__ Bq,   // [N][K] bf16 bits
    const float* __restrict__ bias,
    float* __restrict__ C) {
  __shared__ unsigned short As[2][BM][BK];   // 2 x 8 KB
  __shared__ unsigned short Bs[2][BN][BK];   // 2 x 16 KB

  const int tid  = threadIdx.x;
  const int lane = tid & 63;
  const int wave = tid >> 6;
  const int wm = (wave >> 1) * 32;   // wave row offset in tile
  const int wn = (wave & 1) * 64;    // wave col offset in tile

  const int bn = (blockIdx.x & 31) * BN;   // N/BN = 32
  const int bm = (blockIdx.x >> 5) * BM;   // M/BM = 16

  const int sr = tid >> 3;          // staging row 0..31
  const int sc = (tid & 7) * 8;     // staging col (elements)

  const int fr = lane & 15;          // fragment row (A) / col (B)
  const int fk = (lane >> 4) * 8;    // fragment k offset within 32

  f32x4 acc[2][4] = {};

  // prologue: stage k-tile 0 into buffer 0
  {
    const unsigned short* ga = Aq + (size_t)(bm + sr) * K + sc;
    const unsigned short* gb = Bq + (size_t)(bn + sr) * K + sc;
#pragma unroll
    for (int i = 0; i < 2; ++i)
      gl2lds16(ga + (size_t)i * 32 * K, &As[0][i * 32 + sr][sc]);
#pragma unroll
    for (int i = 0; i < 4; ++i)
      gl2lds16(gb + (size_t)i * 32 * K, &Bs[0][i * 32 + sr][sc]);
  }
  __syncthreads();

  for (int kt = 0; kt < KT; ++kt) {
    const int cur = kt & 1;
    if (kt + 1 < KT) {
      const int k0 = (kt + 1) * BK;
      const unsigned short* ga = Aq + (size_t)(bm + sr) * K + k0 + sc;
      const unsigned short* gb = Bq + (size_t)(bn + sr) * K + k0 + sc;
#pragma unroll
      for (int i = 0; i < 2; ++i)
        gl2lds16(ga + (size_t)i * 32 * K, &As[cur ^ 1][i * 32 + sr][sc]);
#pragma unroll
      for (int i = 0; i < 4; ++i)
        gl2lds16(gb + (size_t)i * 32 * K, &Bs[cur ^ 1][i * 32 + sr][sc]);
    }

#pragma unroll
    for (int ks = 0; ks < 2; ++ks) {
      bf16x8 aF[2], bF[4];
#pragma unroll
      for (int fm = 0; fm < 2; ++fm)
        aF[fm] = *reinterpret_cast<const bf16x8*>(&As[cur][wm + fm * 16 + fr][ks * 32 + fk]);
#pragma unroll
      for (int fn = 0; fn < 4; ++fn)
        bF[fn] = *reinterpret_cast<const bf16x8*>(&Bs[cur][wn + fn * 16 + fr][ks * 32 + fk]);
#pragma unroll
      for (int fm = 0; fm < 2; ++fm)
#pragma unroll
        for (int fn = 0; fn < 4; ++fn)
          acc[fm][fn] = __builtin_amdgcn_mfma_f32_16x16x32_bf16(aF[fm], bF[fn], acc[fm][fn], 0, 0, 0);
    }
    __syncthreads();
  }

  // epilogue: C/D layout col = lane&15, row = (lane>>4)*4 + reg
  const int r0 = bm + wm + (lane >> 4) * 4;
  const int c0 = bn + wn + fr;
#pragma unroll
  for (int fm = 0; fm < 2; ++fm) {
#pragma unroll
    for (int r = 0; r < 4; ++r) {
      float* Crow = C + (size_t)(r0 + fm * 16 + r) * N;
#pragma unroll
      for (int fn = 0; fn < 4; ++fn) {
        int col = c0 + fn * 16;
        Crow[col] = acc[fm][fn][r] + bias[col];
      }
    }
  }
}

extern "C" void kernel_launch(void* const* d_in, const int* in_sizes, int n_in,
                              void* d_out, int out_size, void* d_ws, size_t ws_size,
                              hipStream_t stream) {
  const float* x        = (const float*)d_in[0];
  const float* weight   = (const float*)d_in[1];
  const float* bias     = (const float*)d_in[2];
  const float* w_scales = (const float*)d_in[3];
  const float* w_zeros  = (const float*)d_in[4];
  const float* a_scales = (const float*)d_in[5];
  const float* a_zeros  = (const float*)d_in[6];
  float* out = (float*)d_out;

  unsigned short* xq = (unsigned short*)d_ws;      // M*K bf16
  unsigned short* wq = xq + (size_t)M * K;         // N*K bf16

  const int n4x = M * K / 4;
  fq_kernel<<<n4x / 256, 256, 0, stream>>>(x, a_scales, a_zeros, xq,
                                           (unsigned)(K / 4 - 1), n4x);
  const int n4w = N * K / 4;
  fq_kernel<<<n4w / 256, 256, 0, stream>>>(weight, w_scales, w_zeros, wq,
                                           0xFFFFFFFFu, n4w);

  gemm_kernel<<<(M / BM) * (N / BN), 256, 0, stream>>>(xq, wq, bias, out);
}

// Round 2
// 241.731 us; speedup vs baseline: 1.0064x; 1.0064x over previous
//
#include <hip/hip_runtime.h>
#include <hip/hip_bf16.h>
#include <stdint.h>

#define DI __device__ __forceinline__

typedef float f32x4 __attribute__((ext_vector_type(4)));
typedef __bf16 bf16x8 __attribute__((ext_vector_type(8)));

static constexpr int M = 1024;
static constexpr int N = 4096;
static constexpr int K = 4096;

// ---------------- fake-quant (f32, ref semantics) -> bf16 ----------------
DI unsigned short f2bf(float f) {
  union { __hip_bfloat16 h; unsigned short u; } cv;
  cv.h = __float2bfloat16(f);  // RNE
  return cv.u;
}

__global__ __launch_bounds__(256) void fq_kernel(
    const float* __restrict__ v, const float* __restrict__ scales,
    const float* __restrict__ zeros, unsigned short* __restrict__ out,
    unsigned smask, int n4) {
  const int stride = gridDim.x * blockDim.x;
  for (int t = blockIdx.x * blockDim.x + threadIdx.x; t < n4; t += stride) {
    const int si = (int)((unsigned)t & smask);
    const float s = scales[si], z = zeros[si];
    const float rs = 1.0f / s;            // one divide per 4 elems
    const float4 x = reinterpret_cast<const float4*>(v)[t];
    ushort4 o;
    float q;
    q = rintf(fmaf(x.x, rs, z)); q = fminf(fmaxf(q, 0.0f), 255.0f); o.x = f2bf((q - z) * s);
    q = rintf(fmaf(x.y, rs, z)); q = fminf(fmaxf(q, 0.0f), 255.0f); o.y = f2bf((q - z) * s);
    q = rintf(fmaf(x.z, rs, z)); q = fminf(fmaxf(q, 0.0f), 255.0f); o.z = f2bf((q - z) * s);
    q = rintf(fmaf(x.w, rs, z)); q = fminf(fmaxf(q, 0.0f), 255.0f); o.w = f2bf((q - z) * s);
    reinterpret_cast<ushort4*>(out)[t] = o;
  }
}

// ---------------- bf16 GEMM: C[M,N] = A[M,K] * B[N,K]^T + bias ----------------
// 128x128 tile, 8 waves: wave-pair (w, w+4) shares a 64x64 output tile and
// splits each BK=64 into two k-halves (kh). A is read directly global->VGPR
// (L2-resident via XCD row mapping); B is staged to swizzled double-buffer LDS.
static constexpr int BM = 128, BN = 128, BK = 64;
static constexpr int KT = K / BK;  // 64

DI void gl2lds16(const void* g, void* l) {
  __builtin_amdgcn_global_load_lds(
      (const __attribute__((address_space(1))) void*)g,
      (__attribute__((address_space(3))) void*)l, 16, 0, 0);
}

__global__ __launch_bounds__(512) void gemm_kernel(
    const unsigned short* __restrict__ Aq,   // [M][K] bf16 bits
    const unsigned short* __restrict__ Bq,   // [N][K] bf16 bits
    const float* __restrict__ bias,
    float* __restrict__ C) {
  __shared__ char smem[65536];               // B dbuf (2x16KB) + combine (64KB)
  unsigned short* Bs0 = (unsigned short*)smem;
  unsigned short* Bs1 = (unsigned short*)(smem + 16384);

  const int tid  = threadIdx.x;
  const int lane = tid & 63;
  const int w    = tid >> 6;        // 0..7
  const int kh   = w >> 2;          // k-half of each BK tile
  const int wq4  = w & 3;
  const int wm   = (wq4 >> 1) * 64;
  const int wn   = (wq4 & 1) * 64;
  const int fr   = lane & 15;
  const int fk   = (lane >> 4) * 8; // element offset within 32-k chunk

  const int bm = (blockIdx.x & 7) * BM;    // M-row -> XCD (round-robin)
  const int bn = (blockIdx.x >> 3) * BN;

  // --- B staging (512 threads, 2 gl2lds each per K-tile, swizzled source) ---
  const int sr  = tid >> 3;                 // 0..63
  const int ss  = tid & 7;                  // 16B slot
  const int scw = (ss ^ (sr & 7)) * 8;      // inverse-swizzled source col (elems)
  const unsigned short* bsrc0 = Bq + (size_t)(bn + sr) * K + scw;
  const unsigned short* bsrc1 = bsrc0 + (size_t)64 * K;   // (sr+64)&7 == sr&7
  const int bdst0 = sr * 64 + ss * 8;       // linear LDS dest (elems)
  const int bdst1 = (64 + sr) * 64 + ss * 8;

  // --- A fragment row pointers (direct global) ---
  const unsigned short* arow[4];
#pragma unroll
  for (int fm = 0; fm < 4; ++fm)
    arow[fm] = Aq + (size_t)(bm + wm + fm * 16 + fr) * K + kh * 32 + fk;

  f32x4 acc[4][4] = {};
  bf16x8 aA[4], aB[4];

  // prologue: stage B(0) -> Bs0, load A(0)
  gl2lds16(bsrc0, Bs0 + bdst0);
  gl2lds16(bsrc1, Bs0 + bdst1);
#pragma unroll
  for (int fm = 0; fm < 4; ++fm) aA[fm] = *(const bf16x8*)(arow[fm]);

  auto kstep = [&](int t, unsigned short* cur, unsigned short* nxt,
                   bf16x8 (&aCur)[4], bf16x8 (&aNxt)[4], bool do_next) {
    // own stage of tile t complete (newer in flight: 4 A-loads)
    asm volatile("s_waitcnt vmcnt(4)" ::: "memory");
    __builtin_amdgcn_s_barrier();
    __builtin_amdgcn_sched_barrier(0);
    if (do_next) {
      const size_t ko = (size_t)(t + 1) * BK;
      gl2lds16(bsrc0 + ko, nxt + bdst0);
      gl2lds16(bsrc1 + ko, nxt + bdst1);
#pragma unroll
      for (int fm = 0; fm < 4; ++fm)
        aNxt[fm] = *(const bf16x8*)(arow[fm] + ko);
    }
#pragma unroll
    for (int fn = 0; fn < 4; ++fn) {
      const int row  = wn + fn * 16 + fr;
      const int slot = (kh * 4 + (lane >> 4)) ^ (row & 7);
      const bf16x8 bF = *(const bf16x8*)(cur + row * 64 + slot * 8);
#pragma unroll
      for (int fm = 0; fm < 4; ++fm)
        acc[fm][fn] = __builtin_amdgcn_mfma_f32_16x16x32_bf16(aCur[fm], bF, acc[fm][fn], 0, 0, 0);
    }
  };

  for (int t = 0; t < KT; t += 2) {
    kstep(t,     Bs0, Bs1, aA, aB, true);
    kstep(t + 1, Bs1, Bs0, aB, aA, t + 2 < KT);
  }

  // --- combine k-halves through LDS, add bias, store ---
  __syncthreads();
  float* cb = (float*)smem;  // [4 tiles][64 lanes][16 x f32x4], xor-swizzled
  if (kh == 1) {
#pragma unroll
    for (int fm = 0; fm < 4; ++fm)
#pragma unroll
      for (int fn = 0; fn < 4; ++fn) {
        const int slot = (fm * 4 + fn) ^ (lane & 15);
        *(f32x4*)(cb + ((wq4 * 64 + lane) * 16 + slot) * 4) = acc[fm][fn];
      }
  }
  __syncthreads();
  if (kh == 0) {
#pragma unroll
    for (int fm = 0; fm < 4; ++fm) {
#pragma unroll
      for (int fn = 0; fn < 4; ++fn) {
        const int slot = (fm * 4 + fn) ^ (lane & 15);
        f32x4 o = *(const f32x4*)(cb + ((wq4 * 64 + lane) * 16 + slot) * 4);
        o += acc[fm][fn];
        const int col = bn + wn + fn * 16 + fr;
        const float bv = bias[col];
        const int r0 = bm + wm + fm * 16 + ((lane >> 4) << 2);
#pragma unroll
        for (int r = 0; r < 4; ++r)
          C[(size_t)(r0 + r) * N + col] = o[r] + bv;
      }
    }
  }
}

extern "C" void kernel_launch(void* const* d_in, const int* in_sizes, int n_in,
                              void* d_out, int out_size, void* d_ws, size_t ws_size,
                              hipStream_t stream) {
  const float* x        = (const float*)d_in[0];
  const float* weight   = (const float*)d_in[1];
  const float* bias     = (const float*)d_in[2];
  const float* w_scales = (const float*)d_in[3];
  const float* w_zeros  = (const float*)d_in[4];
  const float* a_scales = (const float*)d_in[5];
  const float* a_zeros  = (const float*)d_in[6];
  float* out = (float*)d_out;

  unsigned short* xq = (unsigned short*)d_ws;      // M*K bf16
  unsigned short* wq = xq + (size_t)M * K;         // N*K bf16

  const int n4x = M * K / 4;
  fq_kernel<<<2048, 256, 0, stream>>>(x, a_scales, a_zeros, xq,
                                      (unsigned)(K / 4 - 1), n4x);
  const int n4w = N * K / 4;
  fq_kernel<<<2048, 256, 0, stream>>>(weight, w_scales, w_zeros, wq,
                                      0xFFFFFFFFu, n4w);

  gemm_kernel<<<(M / BM) * (N / BN), 512, 0, stream>>>(xq, wq, bias, out);
}

// Round 4
// 193.379 us; speedup vs baseline: 1.2580x; 1.2500x over previous
//
#include <hip/hip_runtime.h>
#include <hip/hip_bf16.h>
#include <stdint.h>

#define DI __device__ __forceinline__

typedef float f32x4 __attribute__((ext_vector_type(4)));
typedef __bf16 bf16x8 __attribute__((ext_vector_type(8)));

static constexpr int M = 1024;
static constexpr int N = 4096;
static constexpr int K = 4096;

// ---------------- fused fake-quant (f32, ref semantics) -> bf16 ----------------
DI unsigned short f2bf(float f) {
  union { __hip_bfloat16 h; unsigned short u; } cv;
  cv.h = __float2bfloat16(f);  // RNE
  return cv.u;
}

__global__ __launch_bounds__(256) void fq_kernel(
    const float* __restrict__ x, const float* __restrict__ wt,
    const float* __restrict__ a_scales, const float* __restrict__ a_zeros,
    const float* __restrict__ w_scales, const float* __restrict__ w_zeros,
    unsigned short* __restrict__ xq, unsigned short* __restrict__ wq) {
  constexpr int n4x = M * K / 4;
  constexpr int n4w = N * K / 4;
  const int stride = gridDim.x * blockDim.x;
  for (int t = blockIdx.x * blockDim.x + threadIdx.x; t < n4x + n4w; t += stride) {
    float s, z;
    const float4* src;
    unsigned short* dst;
    int idx;
    if (t < n4x) {
      idx = t;
      const int si = t & (K / 4 - 1);
      s = a_scales[si]; z = a_zeros[si];
      src = reinterpret_cast<const float4*>(x);
      dst = xq;
    } else {
      idx = t - n4x;
      s = w_scales[idx]; z = w_zeros[idx];
      src = reinterpret_cast<const float4*>(wt);
      dst = wq;
    }
    const float rs = 1.0f / s;
    const float4 v = src[idx];
    ushort4 o;
    float q;
    q = rintf(fmaf(v.x, rs, z)); q = fminf(fmaxf(q, 0.0f), 255.0f); o.x = f2bf((q - z) * s);
    q = rintf(fmaf(v.y, rs, z)); q = fminf(fmaxf(q, 0.0f), 255.0f); o.y = f2bf((q - z) * s);
    q = rintf(fmaf(v.z, rs, z)); q = fminf(fmaxf(q, 0.0f), 255.0f); o.z = f2bf((q - z) * s);
    q = rintf(fmaf(v.w, rs, z)); q = fminf(fmaxf(q, 0.0f), 255.0f); o.w = f2bf((q - z) * s);
    reinterpret_cast<ushort4*>(dst)[idx] = o;
  }
}

// ---------------- bf16 GEMM: C[M,N] = A[M,K] * B[N,K]^T + bias ----------------
// 128x128 tile, 512 thr / 8 waves (2M x 2N x 2K-half split). A and B staged
// via global_load_lds into a 3-deep rotating buffer; counted vmcnt(8).
// LDS dest is wave-uniform+lane*16 (HW semantics, m104); XOR swizzle applied
// on the per-lane GLOBAL source col and on the ds_read side (same involution).
static constexpr int BM = 128, BN = 128, BK = 64;
static constexpr int KT = K / BK;  // 64

DI void gl2lds16(const void* g, void* l) {
  __builtin_amdgcn_global_load_lds(
      (const __attribute__((address_space(1))) void*)g,
      (__attribute__((address_space(3))) void*)l, 16, 0, 0);
}

__global__ __launch_bounds__(512) void gemm_kernel(
    const unsigned short* __restrict__ Aq,   // [M][K] bf16 bits
    const unsigned short* __restrict__ Bq,   // [N][K] bf16 bits
    const float* __restrict__ bias,
    float* __restrict__ C) {
  __shared__ char smem[98304];  // 3 x (A 16KB + B 16KB)

  const int tid  = threadIdx.x;
  const int lane = tid & 63;
  const int w    = tid >> 6;        // 0..7
  const int kh   = w >> 2;          // k-half of each BK tile
  const int wq4  = w & 3;
  const int wm   = (wq4 >> 1) * 64;
  const int wn   = (wq4 & 1) * 64;
  const int fr   = lane & 15;

  // XCD swizzle: block i -> XCD i&7. XCD x owns bn in {4x..4x+3} (B working
  // set 4MB = L2-resident) x all 8 bm.
  const int xcd = blockIdx.x & 7;
  const int j   = blockIdx.x >> 3;          // 0..31
  const int bm  = (j & 7) * BM;
  const int bn  = (xcd * 4 + (j >> 3)) * BN;

  // --- staging addresses (HW-linear LDS: wave-uniform base + lane*16B) ---
  // Wave w, call c covers rows c*64 + 8w + (lane>>3), slot lane&7.
  // row&7 == lane>>3, so source-col swizzle is ((lane&7)^(lane>>3))*8.
  const int lrow = lane >> 3;                // 0..7 (== row&7)
  const int scol = ((lane & 7) ^ lrow) * 8;  // pre-swizzled source col (elems)
  const unsigned short* gA0 = Aq + (size_t)(bm +      8 * w + lrow) * K + scol;
  const unsigned short* gA1 = Aq + (size_t)(bm + 64 + 8 * w + lrow) * K + scol;
  const unsigned short* gB0 = Bq + (size_t)(bn +      8 * w + lrow) * K + scol;
  const unsigned short* gB1 = Bq + (size_t)(bn + 64 + 8 * w + lrow) * K + scol;
  const int wofs = w * 1024;                 // wave-uniform LDS byte base

  auto stage = [&](int k0, int s) {
    char* base = smem + s * 32768;
    gl2lds16(gA0 + k0, base + wofs);              // A rows  8w..8w+7
    gl2lds16(gA1 + k0, base + 8192 + wofs);       // A rows 64+8w..
    gl2lds16(gB0 + k0, base + 16384 + wofs);      // B rows  8w..8w+7
    gl2lds16(gB1 + k0, base + 24576 + wofs);      // B rows 64+8w..
  };

  // --- fragment read offsets (swizzled): LDS[r][p] = global[r][p ^ (r&7)] ---
  const int slot = kh * 4 + (lane >> 4);     // wanted global 16B slot
  int aoff[4], boff[4];
#pragma unroll
  for (int f = 0; f < 4; ++f) {
    const int ra = wm + f * 16 + fr;
    aoff[f] = ra * 64 + (slot ^ (ra & 7)) * 8;
    const int rb = wn + f * 16 + fr;
    boff[f] = rb * 64 + (slot ^ (rb & 7)) * 8;
  }

  f32x4 acc[4][4] = {};

  auto compute = [&](int s) {
    const unsigned short* As = (const unsigned short*)(smem + s * 32768);
    const unsigned short* Bs = As + 8192;
    bf16x8 aF[4], bF[4];
#pragma unroll
    for (int f = 0; f < 4; ++f) aF[f] = *(const bf16x8*)(As + aoff[f]);
#pragma unroll
    for (int f = 0; f < 4; ++f) bF[f] = *(const bf16x8*)(Bs + boff[f]);
#pragma unroll
    for (int fm = 0; fm < 4; ++fm)
#pragma unroll
      for (int fn = 0; fn < 4; ++fn)
        acc[fm][fn] = __builtin_amdgcn_mfma_f32_16x16x32_bf16(aF[fm], bF[fn], acc[fm][fn], 0, 0, 0);
  };

#define BAR() do { __builtin_amdgcn_sched_barrier(0); \
                   __builtin_amdgcn_s_barrier(); \
                   __builtin_amdgcn_sched_barrier(0); } while (0)

  // prologue: 2 tiles in flight
  stage(0, 0);
  stage(BK, 1);

  int cur = 0, nxt = 2;
  for (int t = 0; t < KT; ++t) {
    if (t + 2 < KT) {
      stage((t + 2) * BK, nxt);
      asm volatile("s_waitcnt vmcnt(8)" ::: "memory");
    } else if (t + 1 < KT) {
      asm volatile("s_waitcnt vmcnt(4)" ::: "memory");
    } else {
      asm volatile("s_waitcnt vmcnt(0)" ::: "memory");
    }
    BAR();                 // stage(t) visible to all
    compute(cur);
    BAR();                 // reads of buf done before it is restaged
    cur = (cur == 2) ? 0 : cur + 1;
    nxt = (nxt == 2) ? 0 : nxt + 1;
  }
#undef BAR

  // --- combine k-halves through LDS, add bias, store ---
  __syncthreads();
  float* cb = (float*)smem;  // [4 tiles][64 lanes][16 x f32x4], xor-swizzled
  if (kh == 1) {
#pragma unroll
    for (int fm = 0; fm < 4; ++fm)
#pragma unroll
      for (int fn = 0; fn < 4; ++fn) {
        const int sl = (fm * 4 + fn) ^ (lane & 15);
        *(f32x4*)(cb + ((wq4 * 64 + lane) * 16 + sl) * 4) = acc[fm][fn];
      }
  }
  __syncthreads();
  if (kh == 0) {
#pragma unroll
    for (int fm = 0; fm < 4; ++fm) {
#pragma unroll
      for (int fn = 0; fn < 4; ++fn) {
        const int sl = (fm * 4 + fn) ^ (lane & 15);
        f32x4 o = *(const f32x4*)(cb + ((wq4 * 64 + lane) * 16 + sl) * 4);
        o += acc[fm][fn];
        const int col = bn + wn + fn * 16 + fr;
        const float bv = bias[col];
        const int r0 = bm + wm + fm * 16 + ((lane >> 4) << 2);
#pragma unroll
        for (int r = 0; r < 4; ++r)
          C[(size_t)(r0 + r) * N + col] = o[r] + bv;
      }
    }
  }
}

extern "C" void kernel_launch(void* const* d_in, const int* in_sizes, int n_in,
                              void* d_out, int out_size, void* d_ws, size_t ws_size,
                              hipStream_t stream) {
  const float* x        = (const float*)d_in[0];
  const float* weight   = (const float*)d_in[1];
  const float* bias     = (const float*)d_in[2];
  const float* w_scales = (const float*)d_in[3];
  const float* w_zeros  = (const float*)d_in[4];
  const float* a_scales = (const float*)d_in[5];
  const float* a_zeros  = (const float*)d_in[6];
  float* out = (float*)d_out;

  unsigned short* xq = (unsigned short*)d_ws;      // M*K bf16
  unsigned short* wq = xq + (size_t)M * K;         // N*K bf16

  fq_kernel<<<2048, 256, 0, stream>>>(x, weight, a_scales, a_zeros,
                                      w_scales, w_zeros, xq, wq);
  gemm_kernel<<<(M / BM) * (N / BN), 512, 0, stream>>>(xq, wq, bias, out);
}